// Round 1
// baseline (220.267 us; speedup 1.0000x reference)
//
#include <hip/hip_runtime.h>
#include <math.h>

#define N_MEM   50000
#define P_TOT   4096
#define DDIM    256
#define HDIM    480
#define WDIM    640
#define QB      16            // query blocks (4096 points / 256)
#define COPYB   512           // state-copy blocks
#define THR2    0.01f
#define EPSF    1e-8f

// ---- spatial hash grid over mem_pts (setup: uniform in [-8,8]^3) ----
// cell 0.6875m >= 2*RS so a radius query spans <=2 cells/dim (<=8 cells).
// RS=0.15 covers the 0.1m match radius with margin >> fp slop (~1e-4).
// Clamped-trunc cell mapping is monotone, so any true neighbor's cell is
// always inside the query's clamped cell range (degenerate inputs stay correct,
// only slower). Counting sort => no fixed-capacity overflow risk.
#define GDIM    24
#define NCELL   13824         // 24^3
#define GORG    -8.25f
#define GINV    (1.0f/0.6875f)
#define GRS     0.15f
#define CPT     14            // cells per thread in prefix kernel (1024*14 >= 13824)

typedef unsigned long long ull;

// monotone float->uint transform: a<b (float) <=> fsort(a)<fsort(b) (uint)
__device__ __forceinline__ unsigned fsort(float x) {
    unsigned b = __float_as_uint(x);
    return (b & 0x80000000u) ? ~b : (b | 0x80000000u);
}

__device__ __forceinline__ int cell1d(float x) {
    int c = (int)((x - GORG) * GINV);   // trunc; negative args trunc to 0 == clamped floor
    return min(max(c, 0), GDIM - 1);
}

// ---------------- G1: histogram of mem points into cells ----------------
__global__ __launch_bounds__(256) void k_hist(const float* __restrict__ mem_pts,
                                              int* __restrict__ cell_count)
{
    int j = blockIdx.x * 256 + threadIdx.x;
    if (j >= N_MEM) return;
    float mx = mem_pts[j*3+0], my = mem_pts[j*3+1], mz = mem_pts[j*3+2];
    int c = (cell1d(mz) * GDIM + cell1d(my)) * GDIM + cell1d(mx);
    atomicAdd(&cell_count[c], 1);
}

// ---------------- G2: exclusive prefix over 13824 cells (1 block) ----------------
__global__ __launch_bounds__(1024) void k_prefix(const int* __restrict__ cnt,
                                                 int* __restrict__ cstart,
                                                 int* __restrict__ ccur,
                                                 ull* __restrict__ minkey_inv)
{
    __shared__ int s[1024];
    int t = threadIdx.x;
    if (t == 0) *minkey_inv = 0xFFFFFFFFFFFFFFFFULL;   // init before k_scatter's atomicMin
    int base = t * CPT;
    int loc[CPT];
    int sum = 0;
    for (int i = 0; i < CPT; ++i) {
        int idx = base + i;
        int c = (idx < NCELL) ? cnt[idx] : 0;
        loc[i] = sum; sum += c;
    }
    s[t] = sum;
    __syncthreads();
    for (int off = 1; off < 1024; off <<= 1) {
        int a = s[t];
        int b = (t >= off) ? s[t - off] : 0;
        __syncthreads();
        s[t] = a + b;
        __syncthreads();
    }
    int ex = s[t] - sum;                 // exclusive block prefix
    for (int i = 0; i < CPT; ++i) {
        int idx = base + i;
        if (idx < NCELL) { int v = ex + loc[i]; cstart[idx] = v; ccur[idx] = v; }
    }
}

// ---------------- G3: counting-sort scatter + invalid-point global argmin ----------------
// Invalid points all sit at exactly (1e6,1e6,1e6) (ref sets them so), hence share ONE
// global argmin over all mem points: computed here (we read every mem point anyway).
// d2 expression is byte-identical to the query's / previous passing kernel's.
__global__ __launch_bounds__(256) void k_scatter(const float* __restrict__ mem_pts,
                                                 int* __restrict__ ccur,
                                                 int* __restrict__ sorted_idx,
                                                 ull* __restrict__ minkey_inv)
{
    __shared__ ull sred[4];
    int t = threadIdx.x;
    int j = blockIdx.x * 256 + t;
    ull key = 0xFFFFFFFFFFFFFFFFULL;
    if (j < N_MEM) {
        float mx = mem_pts[j*3+0], my = mem_pts[j*3+1], mz = mem_pts[j*3+2];
        int c = (cell1d(mz) * GDIM + cell1d(my)) * GDIM + cell1d(mx);
        int pos = atomicAdd(&ccur[c], 1);
        sorted_idx[pos] = j;
        float px = 1e6f;
        float pp  = px*px + px*px + px*px;
        float dot = px*mx + px*my + px*mz;
        float mm  = mx*mx + my*my + mz*mz;
        float d   = pp - 2.f*dot + mm;
        key = ((ull)fsort(d) << 32) | (unsigned)j;   // lexicographic (d, j) => first-occurrence min
    }
    for (int off = 32; off; off >>= 1) {
        ull o = __shfl_xor(key, off);
        key = o < key ? o : key;
    }
    if ((t & 63) == 0) sred[t >> 6] = key;
    __syncthreads();
    if (t == 0) {
        ull a = sred[0] < sred[1] ? sred[0] : sred[1];
        ull b = sred[2] < sred[3] ? sred[2] : sred[3];
        ull m = a < b ? a : b;
        atomicMin(minkey_inv, m);
    }
}

// ---------------- K_main: fused pix2world + grid NN query (tiny) + state copy (HBM) ----
// blocks [0,QB): 4096 points, 1 thread/point: world transform, then scan <=8 grid
//                cells (~30 candidates) for all j with d2 < THR2. Exact argmin is only
//                consumed when matched (candidates are a superset of all sub-threshold j)
//                or invalid (handled via minkey_inv in k_scan). Single writer => no atomics.
// blocks [QB, QB+COPYB): grid-stride copy of mem_pts/mem_desc -> out (the BW floor).
__global__ __launch_bounds__(256) void k_main(const float* __restrict__ points,
                                              const float* __restrict__ depth,
                                              const float* __restrict__ pose,
                                              const float* __restrict__ Kmat,
                                              const int* __restrict__ cstart,
                                              const int* __restrict__ ccount,
                                              const int* __restrict__ sorted_idx,
                                              const float* __restrict__ mem_pts,
                                              const float* __restrict__ mem_desc,
                                              float4* __restrict__ pts_out,
                                              int* __restrict__ flags_out,
                                              ull* __restrict__ minkey,
                                              float* __restrict__ out_pts,
                                              float* __restrict__ out_desc)
{
    int bid = blockIdx.x;
    int t = threadIdx.x;
    if (bid < QB) {
        int p = bid * 256 + t;
        int b = p >> 9;
        const float* K = Kmat + b * 9;
        float a00=K[0],a01=K[1],a02=K[2],a10=K[3],a11=K[4],a12=K[5],a20=K[6],a21=K[7],a22=K[8];
        float det = a00*(a11*a22-a12*a21) - a01*(a10*a22-a12*a20) + a02*(a10*a21-a11*a20);
        float id = 1.0f/det;
        float i00=(a11*a22-a12*a21)*id, i01=(a02*a21-a01*a22)*id, i02=(a01*a12-a02*a11)*id;
        float i10=(a12*a20-a10*a22)*id, i11=(a00*a22-a02*a20)*id, i12=(a02*a10-a00*a12)*id;
        float i20=(a10*a21-a11*a20)*id, i21=(a01*a20-a00*a21)*id, i22=(a00*a11-a01*a10)*id;

        float u = points[p*2+0], v = points[p*2+1];
        float uc = fminf(fmaxf(u, 0.f), (float)WDIM - 1.001f);
        float vc = fminf(fmaxf(v, 0.f), (float)HDIM - 1.001f);
        float u0 = floorf(uc), v0 = floorf(vc);
        float du = uc - u0, dv = vc - v0;
        int u0i = (int)u0, v0i = (int)v0;
        const float* dm = depth + (size_t)b * HDIM * WDIM;
        float d00 = dm[v0i*WDIM + u0i];
        float d01 = dm[v0i*WDIM + u0i + 1];
        float d10 = dm[(v0i+1)*WDIM + u0i];
        float d11 = dm[(v0i+1)*WDIM + u0i + 1];
        float d = d00*(1.f-du)*(1.f-dv) + d01*du*(1.f-dv) + d10*(1.f-du)*dv + d11*du*dv;

        float cx = (i00*u + i01*v + i02) * d;
        float cy = (i10*u + i11*v + i12) * d;
        float cz = (i20*u + i21*v + i22) * d;
        const float* T = pose + b * 12;
        float wx = T[0]*cx + T[1]*cy + T[2]*cz  + T[3];
        float wy = T[4]*cx + T[5]*cy + T[6]*cz  + T[7];
        float wz = T[8]*cx + T[9]*cy + T[10]*cz + T[11];
        int val = (d > 0.f) && isfinite(wx) && isfinite(wy) && isfinite(wz);
        float px = val ? wx : 1e6f;
        float py = val ? wy : 1e6f;
        float pz = val ? wz : 1e6f;
        pts_out[p] = make_float4(px, py, pz, 0.f);
        flags_out[p] = val;

        ull best = 0xFFFFFFFFFFFFFFFFULL;
        if (val) {
            float pp = px*px + py*py + pz*pz;
            int cx0 = cell1d(px - GRS), cx1 = cell1d(px + GRS);
            int cy0 = cell1d(py - GRS), cy1 = cell1d(py + GRS);
            int cz0 = cell1d(pz - GRS), cz1 = cell1d(pz + GRS);
            for (int zz = cz0; zz <= cz1; ++zz)
                for (int yy = cy0; yy <= cy1; ++yy) {
                    int rowc = (zz * GDIM + yy) * GDIM;
                    for (int xx = cx0; xx <= cx1; ++xx) {
                        int cell = rowc + xx;
                        int s0 = cstart[cell];
                        int n  = ccount[cell];
                        for (int k = s0; k < s0 + n; ++k) {
                            int j = sorted_idx[k];
                            float mx = mem_pts[j*3+0], my = mem_pts[j*3+1], mz = mem_pts[j*3+2];
                            float mm  = mx*mx + my*my + mz*mz;   // same expr as before
                            float dot = px*mx + py*my + pz*mz;
                            float dd2 = pp - 2.f*dot + mm;       // fp expr identical to ref-passing kernel
                            ull key = ((ull)fsort(dd2) << 32) | (unsigned)j;
                            best = key < best ? key : best;      // exact (d, j) lexicographic min
                        }
                    }
                }
        }
        minkey[p] = best;      // single writer per point
    } else {
        const long tid = (long)(bid - QB) * 256 + t;
        const long stride = (long)COPYB * 256;
        const float2* ds = (const float2*)mem_desc;
        float2* dd = (float2*)out_desc;                 // 8B-aligned (offset 600008 B)
        const long ND2 = (long)N_MEM * DDIM / 2;        // 6.4e6 float2
        long k = tid * 4;
        const long stride4 = stride * 4;
        for (; k + 3 < ND2; k += stride4) {             // 4-deep unroll: loads in flight
            float2 a0 = ds[k+0], a1 = ds[k+1], a2 = ds[k+2], a3 = ds[k+3];
            dd[k+0] = a0; dd[k+1] = a1; dd[k+2] = a2; dd[k+3] = a3;
        }
        for (; k < ND2; ++k) dd[k] = ds[k];
        const float2* ps = (const float2*)mem_pts;
        float2* pd = (float2*)out_pts;
        for (long i = tid; i < (long)N_MEM * 3 / 2; i += stride) pd[i] = ps[i];
    }
}

// ---------------- K3: decode keys, scan unmatched -> widx, winner, n_match ----------------
// Invalid points (v=0) take the shared global-argmin key (position (1e6,1e6,1e6)).
__global__ __launch_bounds__(256) void k_scan(const ull* __restrict__ minkey,
                                              int* __restrict__ flags,
                                              const int* __restrict__ next_ptr,
                                              const ull* __restrict__ minkey_inv,
                                              int* __restrict__ widx,
                                              int* __restrict__ winner,
                                              float* __restrict__ dout)
{
    __shared__ int su[256];
    __shared__ int smc[256];
    int t = threadIdx.x;
    int base = t * 16;
    const ull thr_key = ((ull)fsort(THR2)) << 32;   // key<thr_key <=> d<THR2 exactly
    ull inv = *minkey_inv;
    int um[16], iv[16], wvv[16];
    int usum = 0, msum = 0;
    for (int k = 0; k < 16; k++) {
        int v = flags[base + k] & 1;
        ull key = v ? minkey[base + k] : inv;
        int m = (key < thr_key) && v;
        int u = (!m) && v;
        iv[k] = (int)(key & 0xffffffffULL);
        um[k] = u; usum += u; msum += m;
        flags[base + k] = v | (m << 1) | (u << 2);
    }
    su[t] = usum; smc[t] = msum;
    __syncthreads();
    for (int off = 1; off < 256; off <<= 1) {
        int a = su[t], b = (t >= off) ? su[t - off] : 0;
        int c = smc[t], d = (t >= off) ? smc[t - off] : 0;
        __syncthreads();
        su[t] = a + b; smc[t] = c + d;
        __syncthreads();
    }
    int excl = su[t] - usum;
    int np_ = *next_ptr;
    int run = excl;
    for (int k = 0; k < 16; k++) {
        int wv;
        if (um[k]) { run += 1; wv = (np_ + run - 1) % N_MEM; }
        else       { wv = iv[k]; }
        widx[base + k] = wv;
        wvv[k] = wv;
        winner[wv] = -1;                   // init touched slots (racing -1 stores benign)
    }
    __syncthreads();
    for (int k = 0; k < 16; k++)
        atomicMax(&winner[wvv[k]], base + k);   // last-write-wins = max p per slot
    if (t == 255) dout[1] = (float)smc[255];    // n_match
}

// ---------------- K4: fused scatter + per-point cosine ----------------
__global__ __launch_bounds__(256) void k_scatloss(const int* __restrict__ widx,
                                                  const int* __restrict__ flags,
                                                  const int* __restrict__ winner,
                                                  const float* __restrict__ desc,
                                                  const float4* __restrict__ pts,
                                                  const float* __restrict__ mem_pts,
                                                  const float* __restrict__ mem_desc,
                                                  float* __restrict__ out_pts,
                                                  float* __restrict__ out_desc,
                                                  float* __restrict__ cos_ws)
{
    __shared__ float red[16];
    int p = blockIdx.x;
    int t = threadIdx.x;
    int f = flags[p];
    int v = f & 1, m = (f >> 1) & 1, u = (f >> 2) & 1;
    int wi = widx[p];
    int win = (winner[wi] == p);
    if (!m && !win) {                       // unmatched/invalid non-winner: loss only
        if (t == 0) cos_ws[p] = v ? 1.f : 0.f;   // unmatched valid: cos(d,d)=1
        return;
    }
    float dsg = desc[p * DDIM + t];
    float old = mem_desc[(long)wi * DDIM + t];   // for matched, wi == idx[p]
    float val, cosv;
    if (m) {
        float up = old * 0.5f + dsg * 0.5f;
        float sdd = dsg * dsg, smm2 = old * old, sdm = dsg * old, suu = up * up;
        for (int off = 32; off; off >>= 1) {
            sdd  += __shfl_xor(sdd,  off);
            smm2 += __shfl_xor(smm2, off);
            sdm  += __shfl_xor(sdm,  off);
            suu  += __shfl_xor(suu,  off);
        }
        int w = t >> 6;
        if ((t & 63) == 0) { red[w] = sdd; red[4+w] = smm2; red[8+w] = sdm; red[12+w] = suu; }
        __syncthreads();
        float dd  = red[0] + red[1] + red[2] + red[3];
        float mm2 = red[4] + red[5] + red[6] + red[7];
        float dm  = red[8] + red[9] + red[10] + red[11];
        float uu  = red[12] + red[13] + red[14] + red[15];
        cosv = dm / (fmaxf(sqrtf(dd), EPSF) * fmaxf(sqrtf(mm2), EPSF));
        val = up / (sqrtf(uu) + EPSF);
    } else {
        cosv = v ? 1.f : 0.f;
        val = u ? dsg : old;                // invalid winner rewrites old value (np semantics)
    }
    if (win) {
        out_desc[(long)wi * DDIM + t] = val;
        if (t == 0) {
            float px, py, pz;
            if (u) { float4 P = pts[p]; px = P.x; py = P.y; pz = P.z; }
            else   { px = mem_pts[wi*3]; py = mem_pts[wi*3+1]; pz = mem_pts[wi*3+2]; }
            out_pts[wi*3+0] = px; out_pts[wi*3+1] = py; out_pts[wi*3+2] = pz;
        }
    }
    if (t == 0) cos_ws[p] = cosv;
}

// ---------------- K5: final reduction over 4096 points ----------------
__global__ __launch_bounds__(256) void k_final(const float* __restrict__ cos_ws,
                                               const int* __restrict__ flags,
                                               float* __restrict__ dout)
{
    __shared__ float ss[256];
    __shared__ float sv[256];
    int t = threadIdx.x;
    float s = 0.f, v = 0.f;
    for (int k = t; k < P_TOT; k += 256) {
        s += cos_ws[k];
        v += (float)(flags[k] & 1);
    }
    ss[t] = s; sv[t] = v;
    __syncthreads();
    for (int off = 128; off; off >>= 1) {
        if (t < off) { ss[t] += ss[t + off]; sv[t] += sv[t + off]; }
        __syncthreads();
    }
    if (t == 0) {
        float nv = fmaxf(sv[0], 1.f);
        dout[0] = 1.f - ss[0] / nv;
    }
}

extern "C" void kernel_launch(void* const* d_in, const int* in_sizes, int n_in,
                              void* d_out, int out_size, void* d_ws, size_t ws_size,
                              hipStream_t stream)
{
    const float* points   = (const float*)d_in[0];
    const float* depth    = (const float*)d_in[1];
    const float* pose     = (const float*)d_in[2];
    const float* Kmat     = (const float*)d_in[3];
    const float* desc     = (const float*)d_in[4];
    const float* mem_pts  = (const float*)d_in[5];
    const float* mem_desc = (const float*)d_in[6];
    const int*   next_ptr = (const int*)d_in[7];

    float* out      = (float*)d_out;
    float* out_pts  = out + 2;
    float* out_desc = out + 2 + (long)N_MEM * 3;

    char* ws = (char*)d_ws;
    float4* pts_ws   = (float4*)(ws);                //  65536 B
    int* flags_ws    = (int*)(ws + 65536);           //  16384 -> 81920
    int* widx_ws     = (int*)(ws + 81920);           //  16384 -> 98304
    int* winner_ws   = (int*)(ws + 98304);           // 200000 -> 298304
    float* cos_ws    = (float*)(ws + 298304);        //  16384 -> 314688
    ull* minkey_ws   = (ull*)(ws + 314688);          //  32768 -> 347456 (8B aligned)
    int* cell_count  = (int*)(ws + 347456);          //  55296 -> 402752
    int* cell_start  = (int*)(ws + 402752);          //  55296 -> 458048
    int* cell_cursor = (int*)(ws + 458048);          //  55296 -> 513344
    int* sorted_idx  = (int*)(ws + 513344);          // 200000 -> 713344
    ull* minkey_inv  = (ull*)(ws + 713344);          //      8 -> 713352 (8B aligned)

    hipMemsetAsync(cell_count, 0, NCELL * sizeof(int), stream);
    k_hist    <<<196, 256, 0, stream>>>(mem_pts, cell_count);
    k_prefix  <<<1, 1024, 0, stream>>>(cell_count, cell_start, cell_cursor, minkey_inv);
    k_scatter <<<196, 256, 0, stream>>>(mem_pts, cell_cursor, sorted_idx, minkey_inv);
    k_main    <<<QB + COPYB, 256, 0, stream>>>(points, depth, pose, Kmat,
                                               cell_start, cell_count, sorted_idx,
                                               mem_pts, mem_desc,
                                               pts_ws, flags_ws, minkey_ws,
                                               out_pts, out_desc);
    k_scan    <<<1, 256, 0, stream>>>(minkey_ws, flags_ws, next_ptr, minkey_inv,
                                      widx_ws, winner_ws, out);
    k_scatloss<<<P_TOT, 256, 0, stream>>>(widx_ws, flags_ws, winner_ws, desc, pts_ws,
                                          mem_pts, mem_desc, out_pts, out_desc, cos_ws);
    k_final   <<<1, 256, 0, stream>>>(cos_ws, flags_ws, out);
}